// Round 12
// baseline (173.068 us; speedup 1.0000x reference)
//
#include <hip/hip_runtime.h>
#include <hip/hip_bf16.h>
#include <hip/hip_fp16.h>
#include <math.h>

#define BB 8
#define CC 64
#define HH 128
#define WW 128
#define HO 64
#define WO 128
#define OC 64
#define HW (HH * WW)
#define HOWO (HO * WO)

typedef __attribute__((ext_vector_type(8))) short short8;
typedef __attribute__((ext_vector_type(4))) float floatx4;

union BfBits { __hip_bfloat16 h; unsigned short s; };
__device__ __forceinline__ unsigned short f2bf(float f) {
    BfBits b; b.h = __float2bfloat16(f); return b.s;
}
__device__ __forceinline__ float bflo(unsigned int u) {
    return __uint_as_float(u << 16);
}
__device__ __forceinline__ float bfhi(unsigned int u) {
    return __uint_as_float(u & 0xFFFF0000u);
}

// ---------------------------------------------------------------------------
// Kernel A: prep.
//  blocks 0..1023 (b,y): xT[b][y][w][c] bf16 (om staging) and
//    xQ[b][y][w][c] = uint2{pack(x[y][w],x[y][w+1]), pack(x[y+1][w],x[y+1][w+1])}
//    -> ONE 8B coalesced load yields all 4 bilinear corners for a channel.
//  blocks 1024..1059: Wom[32][576]   blocks 1060..1131: W2[k][o][c]
// ---------------------------------------------------------------------------
__global__ __launch_bounds__(512) void prep(
    const float* __restrict__ x,
    const float* __restrict__ w_off, const float* __restrict__ w_msk,
    const float* __restrict__ w_conv,
    unsigned short* __restrict__ xT, uint2* __restrict__ xQ,
    unsigned short* __restrict__ Wom, unsigned short* __restrict__ W2)
{
    __shared__ float T0[64][129];      // (c+w)%32 -> conflict-free both phases
    __shared__ float T1[64][129];
    int tid = threadIdx.x;
    int bx = blockIdx.x;
    if (bx < 1024) {
        int b = bx & 7, y = bx >> 3;
        int wl = tid & 127, c0 = tid >> 7;       // c0 in 0..3
        bool has1 = (y < 127);
#pragma unroll
        for (int i = 0; i < 16; ++i) {
            int c = 4 * i + c0;
            const float* px = x + (((size_t)b * CC + c) * HH + y) * WW + wl;
            T0[c][wl] = px[0];
            T1[c][wl] = has1 ? px[WW] : 0.0f;
        }
        __syncthreads();
        int c = tid & 63, wg = tid >> 6;         // wg in 0..7
#pragma unroll
        for (int i = 0; i < 16; ++i) {
            int wp = wg * 16 + i;
            unsigned int lo0 = f2bf(T0[c][wp]);
            unsigned int hi0 = (wp < 127) ? f2bf(T0[c][wp + 1]) : 0u;
            unsigned int lo1 = f2bf(T1[c][wp]);
            unsigned int hi1 = (wp < 127) ? f2bf(T1[c][wp + 1]) : 0u;
            size_t e = (((size_t)b * HH + y) * WW + wp) * 64 + c;
            xT[e] = (unsigned short)lo0;
            uint2 qv; qv.x = lo0 | (hi0 << 16); qv.y = lo1 | (hi1 << 16);
            xQ[e] = qv;
        }
    } else if (bx < 1060) {
        int i = (bx - 1024) * 512 + tid;         // 18432 = 36*512 exact
        int ch = i / 576, kk = i % 576;
        int xs = kk >> 6, c = kk & 63;
        float v = 0.0f;
        if (ch < 18)      v = w_off[(ch * CC + c) * 9 + xs];
        else if (ch < 27) v = w_msk[((ch - 18) * CC + c) * 9 + xs];
        Wom[i] = f2bf(v);
    } else {
        int i = (bx - 1060) * 512 + tid;         // 36864 = 72*512 exact
        int k = i % 9, c = (i / 9) % CC, o = i / (CC * 9);
        W2[((size_t)k * OC + o) * CC + c] = f2bf(w_conv[i]);
    }
}

// ---------------------------------------------------------------------------
// Kernel B: FUSED om-GEMM + coeffs + sampling + main MFMA (R10 skeleton:
// 18.3 KB LDS -> 8 blocks/CU, per-tap double-buffered S, one barrier/tap).
// Sampling now: per (pos,tap) ONE 8B coalesced xQ load (all 4 corners);
// row base via metaR + readfirstlane (SGPR addressing); fp16 slot-coeffs
// via metaC. In-flight set G[2][8] = 32 VGPR -> fits the regalloc target.
// ---------------------------------------------------------------------------
__global__ __launch_bounds__(256) void fused(
    const unsigned short* __restrict__ xT, const uint2* __restrict__ xQ,
    const unsigned short* __restrict__ Wom, const unsigned short* __restrict__ W2,
    const float* __restrict__ b_off, const float* __restrict__ b_msk,
    float* __restrict__ out)
{
    __shared__ __align__(16) char lds[18304];
    typedef unsigned short XsRow[34][72];
    XsRow* Xs = (XsRow*)lds;                                        // [3][34][72] ph1-2
    unsigned short (*S)[32][64] = (unsigned short(*)[32][64])lds;   // [2][32][64] ph4
    unsigned int* metaR = (unsigned int*)(lds + 8192);              // [288] ph3+
    uint2* metaC = (uint2*)(lds + 9344);                            // [288] ph3+
    float (*omr)[33] = (float(*)[33])(lds + 14720);                 // [27][33]

    int tid = threadIdx.x;
    int lane = tid & 63;
    int wv = __builtin_amdgcn_readfirstlane(tid >> 6);
    int bx = blockIdx.x;               // 2048 = 8b * 64h * 4wt
    int b = bx & 7;
    int rest = bx >> 3;
    int h = rest >> 2;
    int w0 = (rest & 3) * 32;
    int h2 = 2 * h - 1;
    int m16 = lane & 15, q = lane >> 4;

    // ---- phase 1: stage xT slab ----
    for (int u = tid; u < 816; u += 256) {       // 816 = 3*34*8
        int ky = u / 272;
        int rem = u - ky * 272;
        int col = rem >> 3, cb = rem & 7;
        int hy = h2 + ky, wc = w0 - 1 + col;
        short8 v = {0, 0, 0, 0, 0, 0, 0, 0};
        if ((unsigned)hy < (unsigned)HH && (unsigned)wc < (unsigned)WW)
            v = *(const short8*)(xT + (((size_t)b * HH + hy) * WW + wc) * 64 + cb * 8);
        *(short8*)&Xs[ky][col][cb * 8] = v;
    }
    __syncthreads();

    // ---- phase 2: om GEMM ----
    {
        int mt = wv & 1, nt = wv >> 1;
        floatx4 a = (floatx4){0.f, 0.f, 0.f, 0.f};
        const unsigned short* wa = Wom + (mt * 16 + m16) * 576 + q * 8;
#pragma unroll
        for (int t = 0; t < 18; ++t) {
            int xs = t >> 1, ky = xs / 3, kx = xs % 3;
            short8 af = *(const short8*)(wa + t * 32);
            short8 bf = *(const short8*)&Xs[ky][nt * 16 + m16 + kx][(t & 1) * 32 + q * 8];
            a = __builtin_amdgcn_mfma_f32_16x16x32_bf16(af, bf, a, 0, 0, 0);
        }
#pragma unroll
        for (int r = 0; r < 4; ++r) {
            int ch = mt * 16 + q * 4 + r;
            if (ch < 27) omr[ch][nt * 16 + m16] = a[r];
        }
    }
    __syncthreads();   // Xs dead; meta/S may overlay

    // ---- phase 3: slot-coeffs (fp16) + quad row base per (tap,pos) ----
    for (int u = tid; u < 288; u += 256) {
        int kk = u >> 5, pos = u & 31;
        float offy = omr[2 * kk][pos] + b_off[2 * kk];
        float offx = omr[2 * kk + 1][pos] + b_off[2 * kk + 1];
        float mk = 1.0f / (1.0f + __expf(-(omr[18 + kk][pos] + b_msk[kk])));
        float py = offy + (float)(kk / 3) + (float)h2;
        float px = offx + (float)(kk % 3) + (float)(w0 + pos - 1);

        float y0f = floorf(py), x0f = floorf(px);
        float dy = py - y0f, dx = px - x0f;
        int y0 = (int)y0f, x0 = (int)x0f;
        int y1 = y0 + 1, x1 = x0 + 1;
        bool vy0 = (unsigned)y0 < (unsigned)HH;
        bool vy1 = (unsigned)y1 < (unsigned)HH;
        bool vx0 = (unsigned)x0 < (unsigned)WW;
        bool vx1 = (unsigned)x1 < (unsigned)WW;
        float w00 = (1.0f - dy) * (1.0f - dx) * ((vy0 && vx0) ? mk : 0.0f);
        float w01 = (1.0f - dy) * dx          * ((vy0 && vx1) ? mk : 0.0f);
        float w10 = dy * (1.0f - dx)          * ((vy1 && vx0) ? mk : 0.0f);
        float w11 = dy * dx                   * ((vy1 && vx1) ? mk : 0.0f);
        // packed-quad base and corner->slot mapping (invalid corners have w=0)
        int yb = min(max(y0, 0), HH - 2);
        int xb = min(max(x0, 0), WW - 2);
        int a0 = min(max(y0 - yb, 0), 1);
        int a1 = min(max(y1 - yb, 0), 1);
        int e0 = min(max(x0 - xb, 0), 1);
        int e1 = min(max(x1 - xb, 0), 1);
        float r0A = ((e0 == 0) ? w00 : 0.f) + ((e1 == 0) ? w01 : 0.f);
        float r0B = ((e0 == 1) ? w00 : 0.f) + ((e1 == 1) ? w01 : 0.f);
        float r1A = ((e0 == 0) ? w10 : 0.f) + ((e1 == 0) ? w11 : 0.f);
        float r1B = ((e0 == 1) ? w10 : 0.f) + ((e1 == 1) ? w11 : 0.f);
        float c00 = ((a0 == 0) ? r0A : 0.f) + ((a1 == 0) ? r1A : 0.f);
        float c01 = ((a0 == 0) ? r0B : 0.f) + ((a1 == 0) ? r1B : 0.f);
        float c10 = ((a0 == 1) ? r0A : 0.f) + ((a1 == 1) ? r1A : 0.f);
        float c11 = ((a0 == 1) ? r0B : 0.f) + ((a1 == 1) ? r1B : 0.f);

        __half2 hA = __floats2half2_rn(c00, c01);
        __half2 hB = __floats2half2_rn(c10, c11);
        uint2 cc;
        cc.x = __builtin_bit_cast(unsigned int, hA);
        cc.y = __builtin_bit_cast(unsigned int, hB);
        metaC[u] = cc;
        metaR[u] = (unsigned)(yb * WW + xb) * 512u;   // byte offset in xQ slab
    }
    __syncthreads();

    // ---- phase 4: sampling + main MFMA (per-tap barrier, S double-buffer) ----
    int p0 = wv * 8;
    int c = lane;
    int c8 = 8 * c;
    const char* xQb = (const char*)(xQ + (size_t)b * HW * 64);
    floatx4 acc0 = (floatx4){0.f, 0.f, 0.f, 0.f};
    floatx4 acc1 = (floatx4){0.f, 0.f, 0.f, 0.f};
    uint2 G[2][8];

    auto issue = [&](int k, int sel) {
#pragma unroll
        for (int i = 0; i < 8; ++i) {
            unsigned rb = __builtin_amdgcn_readfirstlane(metaR[k * 32 + p0 + i]);
            G[sel][i] = *(const uint2*)(xQb + rb + c8);   // 8B coalesced
        }
    };
    auto store = [&](int k, int buf, int sel) {
#pragma unroll
        for (int i = 0; i < 8; ++i) {
            uint2 cc = metaC[k * 32 + p0 + i];            // broadcast ds_read
            __half2 hA = __builtin_bit_cast(__half2, cc.x);
            __half2 hB = __builtin_bit_cast(__half2, cc.y);
            float v = __low2float(hA) * bflo(G[sel][i].x)
                    + __high2float(hA) * bfhi(G[sel][i].x)
                    + __low2float(hB) * bflo(G[sel][i].y)
                    + __high2float(hB) * bfhi(G[sel][i].y);
            int pos = p0 + i;
            S[buf][pos][((c >> 3) ^ (pos & 7)) * 8 + (c & 7)] = f2bf(v);
        }
    };

    issue(0, 0);
    store(0, 0, 0);

#pragma unroll
    for (int k = 0; k < 9; ++k) {
        __syncthreads();               // S[k&1] visible to all waves
        if (k < 8) issue(k + 1, (k + 1) & 1);   // loads in flight during MFMA
        {
            const unsigned short* wk = W2 + ((size_t)(k * OC) + wv * 16 + m16) * CC + q * 8;
            int buf = k & 1;
#pragma unroll
            for (int s = 0; s < 2; ++s) {
                short8 af = *(const short8*)(wk + s * 32);
                int cb = ((q + 4 * s) ^ (m16 & 7)) * 8;
                short8 bf0 = *(const short8*)&S[buf][m16][cb];
                short8 bf1 = *(const short8*)&S[buf][16 + m16][cb];
                acc0 = __builtin_amdgcn_mfma_f32_16x16x32_bf16(af, bf0, acc0, 0, 0, 0);
                acc1 = __builtin_amdgcn_mfma_f32_16x16x32_bf16(af, bf1, acc1, 0, 0, 0);
            }
        }
        if (k < 8) store(k + 1, (k + 1) & 1, (k + 1) & 1);
    }

    // epilogue: C/D col=lane&15 (pos), row=(lane>>4)*4+reg (o)
#pragma unroll
    for (int nt = 0; nt < 2; ++nt) {
        floatx4 av = nt ? acc1 : acc0;
#pragma unroll
        for (int r = 0; r < 4; ++r) {
            int o = wv * 16 + q * 4 + r;
            out[(((size_t)b * OC + o) * HO + h) * WO + w0 + nt * 16 + m16] = av[r];
        }
    }
}

// ---------------------------------------------------------------------------
extern "C" void kernel_launch(void* const* d_in, const int* in_sizes, int n_in,
                              void* d_out, int out_size, void* d_ws, size_t ws_size,
                              hipStream_t stream)
{
    const float* x      = (const float*)d_in[0];
    const float* w_off  = (const float*)d_in[1];
    const float* b_off  = (const float*)d_in[2];
    const float* w_msk  = (const float*)d_in[3];
    const float* b_msk  = (const float*)d_in[4];
    const float* w_conv = (const float*)d_in[5];
    float* out = (float*)d_out;

    // workspace ~84 MB: xQ(67.1) + xT(16.8) + weights
    uint2* xQ = (uint2*)d_ws;                                      // 8*HW*64 * 8B
    unsigned short* xT = (unsigned short*)(xQ + (size_t)BB * HW * 64);
    unsigned short* Wom = xT + (size_t)BB * HW * 64;               // 18432
    unsigned short* W2 = Wom + 32 * 576;                           // 36864

    prep<<<dim3(1132), dim3(512), 0, stream>>>(x, w_off, w_msk, w_conv,
                                               xT, xQ, Wom, W2);
    fused<<<dim3(2048), dim3(256), 0, stream>>>(xT, xQ, Wom, W2,
                                                b_off, b_msk, out);
}